// Round 2
// baseline (1132.556 us; speedup 1.0000x reference)
//
#include <hip/hip_runtime.h>

#define DD   1024
#define NHH  16
#define HDD  64
#define BB   2
#define SS   2048
#define MT   (BB*SS)   // 4096
#define NSPLIT 2

typedef __attribute__((ext_vector_type(8))) __bf16 bf16x8;
typedef __attribute__((ext_vector_type(4))) float  floatx4;
typedef __attribute__((ext_vector_type(4))) short  shortx4;
typedef __attribute__((ext_vector_type(4))) int    intx4;

static __device__ __forceinline__ short bf16_of(float f) {
    unsigned u = __builtin_bit_cast(unsigned, f);
    u = (u + 0x7fffu + ((u >> 16) & 1u)) >> 16;
    return (short)u;
}

static __device__ __forceinline__ void async_copy16(const short* g, short* l) {
    __builtin_amdgcn_global_load_lds(
        (const __attribute__((address_space(1))) unsigned int*)g,
        (__attribute__((address_space(3))) unsigned int*)l,
        16, 0, 0);
}

// ---------------- cast fp32 -> bf16 (vectorized x4) ----------------
__global__ void cast_f32_to_bf16(const float* __restrict__ in,
                                 short* __restrict__ out, int n4) {
    int i = blockIdx.x * blockDim.x + threadIdx.x;
    if (i >= n4) return;
    floatx4 f = ((const floatx4*)in)[i];
    shortx4 o;
    o[0] = bf16_of(f[0]); o[1] = bf16_of(f[1]);
    o[2] = bf16_of(f[2]); o[3] = bf16_of(f[3]);
    ((shortx4*)out)[i] = o;
}

// ---------------- transpose + cast weight, with head-grouping permutes ------
// mode 0 (Wq/Wk/Wv): Wt[perm(o)][i] = W[i][o],  perm(o)=((o&15)<<6)|(o>>4)
//   -> GEMM n' = h*64+d: block of 64 n' = one full head (coalesced out writes)
// mode 1 (Wo): Wt[o][i'] = W[src(i')][o], src(i')=((i'&63)<<4)|(i'>>6)
//   -> matches attn output stored as c' = h*64+d
__global__ void transpose_cast_w(const float* __restrict__ W,
                                 short* __restrict__ Wt, int mode) {
    __shared__ float tile[32][33];
    int tx = threadIdx.x & 31, ty = threadIdx.x >> 5;
    int o0 = blockIdx.x * 32, i0 = blockIdx.y * 32;
#pragma unroll
    for (int r = 0; r < 32; r += 8) {
        int irow = i0 + ty + r;
        int srow = (mode == 1) ? (((irow & 63) << 4) | (irow >> 6)) : irow;
        tile[ty + r][tx] = W[(size_t)srow * DD + o0 + tx];
    }
    __syncthreads();
#pragma unroll
    for (int r = 0; r < 32; r += 8) {
        int orow = o0 + ty + r;
        int drow = (mode == 0) ? (((orow & 15) << 6) | (orow >> 4)) : orow;
        Wt[(size_t)drow * DD + i0 + tx] = bf16_of(tile[tx][ty + r]);
    }
}

// ---------------- tiled GEMM: Y = X @ Wt^T + b ----------------
// X [4096][1024] bf16 row-major, Wt [n'][k] bf16. BM=128 BN=64 BK=32, 256 thr.
// n' = h*64+d (modes 0/1): block n-range = exactly one head.
// mode 0: out bf16 [b][h][l][d]  (contiguous 16KB per block, LDS-restaged)
// mode 1: out bf16 [b][h][d][l]  (V transposed, LDS-restaged)
// mode 2: out fp32 [m][n]        (final projection, unpermuted n)
__global__ __launch_bounds__(256) void gemm_tiled(
    const short* __restrict__ X, const short* __restrict__ Wt,
    const float* __restrict__ bias, void* __restrict__ out, int mode) {
    __shared__ short As[128 * 32];
    __shared__ short Bs[64 * 32];
    __shared__ __align__(16) short Cs[128 * 72];   // mode1 uses [64][136] view
    int t = threadIdx.x;
    int wave = t >> 6, lane = t & 63;
    int quad = lane >> 4, lr = lane & 15;
    int wm = wave & 1, wn = wave >> 1;
    int m0 = blockIdx.x * 128, n0 = blockIdx.y * 64;

    int arow = t >> 2, acol = (t & 3) * 8;
    floatx4 acc[4][2] = {};

    for (int k0 = 0; k0 < DD; k0 += 32) {
        async_copy16(X + (size_t)(m0 + arow) * DD + k0 + acol,       As + t * 8);
        async_copy16(X + (size_t)(m0 + 64 + arow) * DD + k0 + acol,  As + 2048 + t * 8);
        async_copy16(Wt + (size_t)(n0 + arow) * DD + k0 + acol,      Bs + t * 8);
        __syncthreads();
        bf16x8 a[4], bb[2];
#pragma unroll
        for (int mi = 0; mi < 4; mi++)
            a[mi] = *(const bf16x8*)(As + (wm * 64 + mi * 16 + lr) * 32 + quad * 8);
#pragma unroll
        for (int ni = 0; ni < 2; ni++)
            bb[ni] = *(const bf16x8*)(Bs + (wn * 32 + ni * 16 + lr) * 32 + quad * 8);
#pragma unroll
        for (int mi = 0; mi < 4; mi++)
#pragma unroll
            for (int ni = 0; ni < 2; ni++)
                acc[mi][ni] = __builtin_amdgcn_mfma_f32_16x16x32_bf16(
                    a[mi], bb[ni], acc[mi][ni], 0, 0, 0);
        __syncthreads();
    }

    if (mode == 2) {
#pragma unroll
        for (int mi = 0; mi < 4; mi++)
#pragma unroll
        for (int ni = 0; ni < 2; ni++)
#pragma unroll
        for (int r = 0; r < 4; r++) {
            int m = m0 + wm * 64 + mi * 16 + quad * 4 + r;
            int n = n0 + wn * 32 + ni * 16 + lr;
            ((float*)out)[(size_t)m * DD + n] = acc[mi][ni][r] + bias[n];
        }
        return;
    }

    // modes 0/1: stage to LDS, then fully coalesced writes
#pragma unroll
    for (int mi = 0; mi < 4; mi++)
#pragma unroll
    for (int ni = 0; ni < 2; ni++)
#pragma unroll
    for (int r = 0; r < 4; r++) {
        int nc = wn * 32 + ni * 16 + lr;
        int np = n0 + nc;
        float y = acc[mi][ni][r] + bias[((np & 63) << 4) | (np >> 6)];
        int mr = wm * 64 + mi * 16 + quad * 4 + r;
        if (mode == 0) Cs[mr * 72 + nc] = bf16_of(y);
        else           Cs[nc * 136 + mr] = bf16_of(y);
    }
    __syncthreads();
    int b = m0 >> 11, lbase = m0 & (SS - 1);
    int h = n0 >> 6;
    short* op = (short*)out;
    if (mode == 0) {
        int row = t >> 1, cg = (t & 1) * 32;
        const intx4* src = (const intx4*)(Cs + row * 72 + cg);
        intx4* dst = (intx4*)(op + (((size_t)(b * NHH + h) * SS) + lbase + row) * HDD + cg);
#pragma unroll
        for (int j = 0; j < 4; j++) dst[j] = src[j];
    } else {
        int d = t >> 2, cg = (t & 3) * 32;
        const intx4* src = (const intx4*)(Cs + d * 136 + cg);
        intx4* dst = (intx4*)(op + (((size_t)(b * NHH + h) * HDD) + d) * SS + lbase + cg);
#pragma unroll
        for (int j = 0; j < 4; j++) dst[j] = src[j];
    }
}

// ---------------- scores + softmax(over h), all in registers ----------------
// wave owns a 16x16 (l,n) tile, loops 16 heads; softmax over h is in-lane.
// No LDS, no barriers. probs written coalesced (h-contiguous 64B per pair).
__global__ __launch_bounds__(256, 4) void score_softmax(
    const short* __restrict__ qws, const short* __restrict__ kws,
    float* __restrict__ probs) {
    int t = threadIdx.x, wave = t >> 6, lane = t & 63;
    int quad = lane >> 4, lr = lane & 15;
    int bid = blockIdx.x;               // = b*4096 + lt*32 + ntg
    int ntg = bid & 31;
    int lt  = (bid >> 5) & 127;
    int b   = bid >> 12;
    int nt  = ntg * 4 + wave;
    int l0 = lt * 16, n0 = nt * 16;

    const size_t hstride = (size_t)SS * HDD;
    const short* qb = qws + (size_t)b * NHH * hstride + (size_t)(l0 + lr) * HDD + quad * 8;
    const short* kb = kws + (size_t)b * NHH * hstride + (size_t)(n0 + lr) * HDD + quad * 8;

    floatx4 sc[16];
#pragma unroll
    for (int h = 0; h < 16; h++) {
        bf16x8 a0 = *(const bf16x8*)(qb + h * hstride);
        bf16x8 a1 = *(const bf16x8*)(qb + h * hstride + 32);
        bf16x8 b0 = *(const bf16x8*)(kb + h * hstride);
        bf16x8 b1 = *(const bf16x8*)(kb + h * hstride + 32);
        floatx4 s = {};
        s = __builtin_amdgcn_mfma_f32_16x16x32_bf16(a0, b0, s, 0, 0, 0);
        s = __builtin_amdgcn_mfma_f32_16x16x32_bf16(a1, b1, s, 0, 0, 0);
        s[0] *= 0.125f; s[1] *= 0.125f; s[2] *= 0.125f; s[3] *= 0.125f;
        sc[h] = s;
    }

    // softmax over h, per output row r (all in registers)
#pragma unroll
    for (int r = 0; r < 4; r++) {
        float mx = sc[0][r];
#pragma unroll
        for (int h = 1; h < 16; h++) mx = fmaxf(mx, sc[h][r]);
        float sum = 0.f;
#pragma unroll
        for (int h = 0; h < 16; h++) {
            float e = __expf(sc[h][r] - mx);
            sc[h][r] = e; sum += e;
        }
        float inv = 1.f / sum;
#pragma unroll
        for (int h = 0; h < 16; h++) sc[h][r] *= inv;
    }

    // write probs: lane owns 4 (l,n) pairs x 16 contiguous h floats
#pragma unroll
    for (int r = 0; r < 4; r++) {
        float* gp = probs + ((size_t)(b * SS + l0 + quad * 4 + r) * SS + n0 + lr) * NHH;
#pragma unroll
        for (int j = 0; j < 4; j++) {
            floatx4 w;
            w[0] = sc[4*j+0][r]; w[1] = sc[4*j+1][r];
            w[2] = sc[4*j+2][r]; w[3] = sc[4*j+3][r];
            ((floatx4*)gp)[j] = w;
        }
    }
}

// ---------------- P @ V: re-read probs (coalesced), head-parallel MFMA ------
// block = 512 thr = 8 waves (2 heads/wave). 2 barriers per 32-n tile.
__global__ __launch_bounds__(512) void pv_kernel(
    const float* __restrict__ probs, const short* __restrict__ vtws,
    float* __restrict__ partial) {
    __shared__ __align__(16) short Ps[16 * 16 * 40];  // [h][l][n pad40]
    int t = threadIdx.x, wave = t >> 6, lane = t & 63;
    int quad = lane >> 4, lr = lane & 15;
    int cc = blockIdx.x & (NSPLIT - 1);
    int lt = (blockIdx.x >> 1) & 127;
    int b  = blockIdx.x >> 8;
    int l0 = lt * 16;
    int ls = t >> 5, ns = t & 31;       // staging coords: 16 l x 32 n

    const float* gpb = probs + ((size_t)(b * SS + l0 + ls) * SS + ns) * NHH;
    floatx4 acc[2][4] = {};
    const int NT = SS / 32 / NSPLIT;    // 32 tiles

    for (int it = 0; it < NT; it++) {
        int n0 = (cc * NT + it) * 32;
        const floatx4* gv = (const floatx4*)(gpb + (size_t)n0 * NHH);
        floatx4 f0 = gv[0], f1 = gv[1], f2 = gv[2], f3 = gv[3];
        __syncthreads();                 // prev tile's Ps reads done
        short* pw = Ps + ls * 40 + ns;
        pw[0*640] = bf16_of(f0[0]); pw[1*640] = bf16_of(f0[1]);
        pw[2*640] = bf16_of(f0[2]); pw[3*640] = bf16_of(f0[3]);
        pw[4*640] = bf16_of(f1[0]); pw[5*640] = bf16_of(f1[1]);
        pw[6*640] = bf16_of(f1[2]); pw[7*640] = bf16_of(f1[3]);
        pw[8*640] = bf16_of(f2[0]); pw[9*640] = bf16_of(f2[1]);
        pw[10*640] = bf16_of(f2[2]); pw[11*640] = bf16_of(f2[3]);
        pw[12*640] = bf16_of(f3[0]); pw[13*640] = bf16_of(f3[1]);
        pw[14*640] = bf16_of(f3[2]); pw[15*640] = bf16_of(f3[3]);
        __syncthreads();                 // Ps ready
#pragma unroll
        for (int hh = 0; hh < 2; hh++) {
            int h = wave * 2 + hh;
            bf16x8 pa = *(const bf16x8*)(Ps + (h * 16 + lr) * 40 + quad * 8);
            const short* vh = vtws + ((size_t)(b * NHH + h) * HDD) * SS;
#pragma unroll
            for (int db = 0; db < 4; db++) {
                bf16x8 bv = *(const bf16x8*)(vh + (size_t)(db * 16 + lr) * SS + n0 + quad * 8);
                acc[hh][db] = __builtin_amdgcn_mfma_f32_16x16x32_bf16(pa, bv, acc[hh][db], 0, 0, 0);
            }
        }
    }

    // partial out: c' = h*64+d (matches permuted Wo), coalesced 64B per quad
    float* pc = partial + (size_t)cc * MT * DD;
#pragma unroll
    for (int hh = 0; hh < 2; hh++)
#pragma unroll
    for (int db = 0; db < 4; db++)
#pragma unroll
    for (int r = 0; r < 4; r++) {
        int h = wave * 2 + hh;
        pc[((size_t)(b * SS + l0 + quad * 4 + r)) * DD + h * 64 + db * 16 + lr] =
            acc[hh][db][r];
    }
}

// ---------------- reduce NSPLIT partials -> bf16 aout [m][c'] ----------------
__global__ void reduce_partials(const float* __restrict__ pa,
                                short* __restrict__ aout) {
    size_t i = (size_t)blockIdx.x * blockDim.x + threadIdx.x;
    floatx4 a = ((const floatx4*)pa)[i];
    floatx4 b = ((const floatx4*)pa)[i + (size_t)MT * DD / 4];
    shortx4 o;
    o[0] = bf16_of(a[0] + b[0]); o[1] = bf16_of(a[1] + b[1]);
    o[2] = bf16_of(a[2] + b[2]); o[3] = bf16_of(a[3] + b[3]);
    ((shortx4*)aout)[i] = o;
}

extern "C" void kernel_launch(void* const* d_in, const int* in_sizes, int n_in,
                              void* d_out, int out_size, void* d_ws, size_t ws_size,
                              hipStream_t stream) {
    const float* query = (const float*)d_in[0];
    const float* key_  = (const float*)d_in[1];
    const float* value = (const float*)d_in[2];
    const float* Wq = (const float*)d_in[3];
    const float* bq = (const float*)d_in[4];
    const float* Wk = (const float*)d_in[5];
    const float* bk = (const float*)d_in[6];
    const float* Wv = (const float*)d_in[7];
    const float* bv = (const float*)d_in[8];
    const float* Wo = (const float*)d_in[9];
    const float* bo = (const float*)d_in[10];

    float* out   = (float*)d_out;
    float* probs = out + (size_t)MT * DD;

    const size_t SZ_X = (size_t)MT * DD;
    const size_t SZ_W = (size_t)DD * DD;
    short* ws   = (short*)d_ws;
    short* wto  = ws;
    short* qws  = wto + SZ_W;
    short* kws  = qws + SZ_X;
    short* vtws = kws + SZ_X;
    short* aout = vtws + SZ_X;
    short* xq   = aout + SZ_X;
    short* xk   = xq + SZ_X;
    short* xv   = xk + SZ_X;
    short* wtq  = xv + SZ_X;
    short* wtk  = wtq + SZ_W;
    short* wtv  = wtk + SZ_W;
    float* partial = (float*)xq;   // NSPLIT*16.8MB, live only after projections

    int n4 = (int)(SZ_X / 4);
    cast_f32_to_bf16<<<n4 / 256, 256, 0, stream>>>(query, xq, n4);
    cast_f32_to_bf16<<<n4 / 256, 256, 0, stream>>>(key_,  xk, n4);
    cast_f32_to_bf16<<<n4 / 256, 256, 0, stream>>>(value, xv, n4);

    transpose_cast_w<<<dim3(32, 32), 256, 0, stream>>>(Wq, wtq, 0);
    transpose_cast_w<<<dim3(32, 32), 256, 0, stream>>>(Wk, wtk, 0);
    transpose_cast_w<<<dim3(32, 32), 256, 0, stream>>>(Wv, wtv, 0);
    transpose_cast_w<<<dim3(32, 32), 256, 0, stream>>>(Wo, wto, 1);

    gemm_tiled<<<dim3(32, 16), 256, 0, stream>>>(xq, wtq, bq, qws, 0);
    gemm_tiled<<<dim3(32, 16), 256, 0, stream>>>(xk, wtk, bk, kws, 0);
    gemm_tiled<<<dim3(32, 16), 256, 0, stream>>>(xv, wtv, bv, vtws, 1);

    score_softmax<<<BB * 128 * 32, 256, 0, stream>>>(qws, kws, probs);

    pv_kernel<<<BB * 128 * NSPLIT, 512, 0, stream>>>(probs, vtws, partial);

    reduce_partials<<<(int)(SZ_X / 4 / 256), 256, 0, stream>>>(partial, aout);

    gemm_tiled<<<dim3(32, 16), 256, 0, stream>>>(aout, wto, bo, out, 2);
}